// Round 1
// baseline (386.449 us; speedup 1.0000x reference)
//
#include <hip/hip_runtime.h>
#include <math.h>

#define TWO_PI 6.28318530717958647692f

// B=64, Nt=64, Ns=4096, C=256, hs=64, WIN=2 -> 1024 windows/batch, TOPK=3, GH=GW=4

// ---------------- Kernel 1: z_max[b,c] = max_n z[b,n,c] ----------------
__global__ void k_zmax(const float* __restrict__ z, float* __restrict__ zmax) {
    int b = blockIdx.x;          // 64 blocks
    int c = threadIdx.x;         // 256 threads
    const float* zp = z + (size_t)b * 64 * 256 + c;
    float m = -INFINITY;
#pragma unroll
    for (int n = 0; n < 64; ++n) m = fmaxf(m, zp[n * 256]);
    zmax[b * 256 + c] = m;
}

// ---------------- Kernel 2: resp[b,t] = dot(x[b,t,:], zmax[b,:]) ----------------
// grid = 8192 blocks x 256 threads; 128 blocks/batch; each block: 32 tokens (8 iters x 4 waves)
__global__ void k_resp(const float* __restrict__ x, const float* __restrict__ zmax,
                       float* __restrict__ resp) {
    int blk  = blockIdx.x;
    int b    = blk >> 7;
    int jl   = blk & 127;
    int wave = threadIdx.x >> 6;
    int lane = threadIdx.x & 63;
    float4 zm = ((const float4*)(zmax + b * 256))[lane];
    const float4* xb = (const float4*)(x + (size_t)b * 4096 * 256);
#pragma unroll
    for (int it = 0; it < 8; ++it) {
        int tok = jl * 32 + it * 4 + wave;
        float4 v = xb[(size_t)tok * 64 + lane];
        float d = v.x * zm.x + v.y * zm.y + v.z * zm.z + v.w * zm.w;
#pragma unroll
        for (int off = 32; off > 0; off >>= 1) d += __shfl_down(d, off, 64);
        if (lane == 0) resp[b * 4096 + tok] = d;
    }
}

// ---------------- Kernel 3: window means + per-batch top-3 ----------------
// 64 blocks (one per batch) x 256 threads
__global__ void k_topk(const float* __restrict__ resp, int* __restrict__ idxout) {
    __shared__ float wmean[1024];
    __shared__ float rv[256];
    __shared__ int   ri[256];
    int b   = blockIdx.x;
    int tid = threadIdx.x;
    const float* rb = resp + b * 4096;
    for (int widx = tid; widx < 1024; widx += 256) {
        int h0 = (widx >> 5) << 1;
        int w0 = (widx & 31) << 1;
        int base = h0 * 64 + w0;
        float s = rb[base] + rb[base + 1] + rb[base + 64] + rb[base + 65];
        wmean[widx] = s * 0.25f;
    }
    __syncthreads();
    for (int k = 0; k < 3; ++k) {
        float bv = -INFINITY;
        int   bi = 1 << 30;
        for (int widx = tid; widx < 1024; widx += 256) {
            float v = wmean[widx];
            if (v > bv || (v == bv && widx < bi)) { bv = v; bi = widx; }
        }
        rv[tid] = bv; ri[tid] = bi;
        __syncthreads();
        for (int s = 128; s > 0; s >>= 1) {
            if (tid < s) {
                float v2 = rv[tid + s]; int i2 = ri[tid + s];
                if (v2 > rv[tid] || (v2 == rv[tid] && i2 < ri[tid])) { rv[tid] = v2; ri[tid] = i2; }
            }
            __syncthreads();
        }
        if (tid == 0) {
            idxout[b * 3 + k] = ri[0];
            wmean[ri[0]] = -INFINITY;
        }
        __syncthreads();
    }
}

// ---------------- Kernel 4: gather + bilinear 2x2->4x4 + gabor modulate ----------------
// grid = B*TOPK = 192 blocks x 256 threads
__global__ void k_out(const float* __restrict__ x, const int* __restrict__ idxbuf,
                      const float* __restrict__ theta, const float* __restrict__ sigma,
                      const float* __restrict__ lam,   const float* __restrict__ psi,
                      const float* __restrict__ gamma, const float* __restrict__ wgt,
                      float* __restrict__ out) {
    __shared__ float Xs[4 * 256];
    __shared__ float gm[16];
    int b = blockIdx.x / 3;
    int k = blockIdx.x % 3;
    int tid  = threadIdx.x;
    int tok  = tid >> 6;   // 0..3 = h2*2+w2
    int lane = tid & 63;

    int widx = idxbuf[b * 3 + k];
    int h0 = (widx >> 5) << 1;
    int w0 = (widx & 31) << 1;
    int token_id = (h0 + (tok >> 1)) * 64 + w0 + (tok & 1);
    float4 v = ((const float4*)(x + ((size_t)b * 4096 + token_id) * 256))[lane];
    ((float4*)Xs)[tok * 64 + lane] = v;

    if (tid < 16) {
        int p = tid;
        float yy = (float)(p >> 2) - 1.5f;
        float xx = (float)(p & 3) - 1.5f;
        float acc = 0.0f;
        for (int kk = 0; kk < 16; ++kk) {
            float th = theta[kk] * TWO_PI;
            float sn, cs;
            sincosf(th, &sn, &cs);
            float xp = xx * cs + yy * sn;
            float yp = -xx * sn + yy * cs;
            float sig = sigma[kk] + 0.5f;
            float lmb = lam[kk] + 0.5f;
            float gam = gamma[kk];
            float env = expf(-(xp * xp + gam * gam * yp * yp) / (2.0f * sig * sig));
            float car = cosf(TWO_PI * xp / lmb + psi[kk]);
            acc += wgt[kk] * env * car;
        }
        gm[p] = 1.0f + acc;
    }
    __syncthreads();

    const float WT[4] = {1.0f, 0.75f, 0.25f, 0.0f};
    float4 x00 = ((const float4*)Xs)[0 * 64 + lane];
    float4 x01 = ((const float4*)Xs)[1 * 64 + lane];
    float4 x10 = ((const float4*)Xs)[2 * 64 + lane];
    float4 x11 = ((const float4*)Xs)[3 * 64 + lane];
    float4* ob = (float4*)(out + ((size_t)b * 48 + k * 16) * 256);
#pragma unroll
    for (int it = 0; it < 4; ++it) {
        int p  = it * 4 + (tid >> 6);
        int gy = p >> 2, gx = p & 3;
        float wy0 = WT[gy], wy1 = 1.0f - wy0;
        float wx0 = WT[gx], wx1 = 1.0f - wx0;
        float g = gm[p];
        float4 r;
        r.x = g * (wy0 * (wx0 * x00.x + wx1 * x01.x) + wy1 * (wx0 * x10.x + wx1 * x11.x));
        r.y = g * (wy0 * (wx0 * x00.y + wx1 * x01.y) + wy1 * (wx0 * x10.y + wx1 * x11.y));
        r.z = g * (wy0 * (wx0 * x00.z + wx1 * x01.z) + wy1 * (wx0 * x10.z + wx1 * x11.z));
        r.w = g * (wy0 * (wx0 * x00.w + wx1 * x01.w) + wy1 * (wx0 * x10.w + wx1 * x11.w));
        ob[(size_t)p * 64 + lane] = r;
    }
}

extern "C" void kernel_launch(void* const* d_in, const int* in_sizes, int n_in,
                              void* d_out, int out_size, void* d_ws, size_t ws_size,
                              hipStream_t stream) {
    const float* z     = (const float*)d_in[0];
    const float* x     = (const float*)d_in[1];
    const float* theta = (const float*)d_in[2];
    const float* sigma = (const float*)d_in[3];
    const float* lam   = (const float*)d_in[4];
    const float* psi   = (const float*)d_in[5];
    const float* gamma = (const float*)d_in[6];
    const float* wgt   = (const float*)d_in[7];
    float* out = (float*)d_out;

    float* ws    = (float*)d_ws;
    float* zmax  = ws;                 // 64*256
    float* resp  = ws + 16384;         // 64*4096
    int*   idxb  = (int*)(ws + 16384 + 262144);  // 64*3

    k_zmax<<<64, 256, 0, stream>>>(z, zmax);
    k_resp<<<8192, 256, 0, stream>>>(x, zmax, resp);
    k_topk<<<64, 256, 0, stream>>>(resp, idxb);
    k_out<<<192, 256, 0, stream>>>(x, idxb, theta, sigma, lam, psi, gamma, wgt, out);
}

// Round 2
// 383.995 us; speedup vs baseline: 1.0064x; 1.0064x over previous
//
#include <hip/hip_runtime.h>
#include <math.h>

#define TWO_PI 6.28318530717958647692f

// B=64, Nt=64, Ns=4096, C=256, hs=64, WIN=2 -> 32x32=1024 windows/batch, TOPK=3, GH=GW=4

// ---------------- Kernel 1: z_max[b,c] = max_n z[b,n,c] ----------------
__global__ void k_zmax(const float* __restrict__ z, float* __restrict__ zmax) {
    int b = blockIdx.x;          // 64 blocks
    int c = threadIdx.x;         // 256 threads
    const float* zp = z + (size_t)b * 64 * 256 + c;
    float m = -INFINITY;
#pragma unroll
    for (int n = 0; n < 64; ++n) m = fmaxf(m, zp[n * 256]);
    zmax[b * 256 + c] = m;
}

// ---------------- Kernel 2: window means directly ----------------
// wmean[b, wh*32+ww] = 0.25 * sum_{2x2 tokens} dot(x[b,tok,:], zmax[b,:])
// grid = 64 batches * 32 window-rows = 2048 blocks x 256 threads (4 waves).
// Each wave-pass computes ONE window: 16-lane group per token (4 groups),
// each lane covers 16 channels (4 x float4), 6 shfl_xor per window.
__global__ void k_wmean(const float* __restrict__ x, const float* __restrict__ zmax,
                        float* __restrict__ wmean) {
    int blk  = blockIdx.x;
    int b    = blk >> 5;         // batch
    int wh   = blk & 31;         // window row (0..31)
    int wave = threadIdx.x >> 6; // 0..3
    int lane = threadIdx.x & 63;
    int g    = lane >> 4;        // token within 2x2 window: (g>>1, g&1)
    int q    = lane & 15;        // lane within 16-lane group

    // zmax fragment: float4 indices q, q+16, q+32, q+48
    const float4* zm4 = (const float4*)(zmax + b * 256);
    float4 zm0 = zm4[q];
    float4 zm1 = zm4[q + 16];
    float4 zm2 = zm4[q + 32];
    float4 zm3 = zm4[q + 48];

    const float4* xb = (const float4*)(x + (size_t)b * 4096 * 256);
    int trow = (2 * wh + (g >> 1)) * 64;   // token row base
    float* wout = wmean + b * 1024 + wh * 32;

#pragma unroll
    for (int p = 0; p < 8; ++p) {
        int ww  = p * 4 + wave;
        int tok = trow + 2 * ww + (g & 1);
        const float4* tp = xb + (size_t)tok * 64;
        float4 v0 = tp[q];
        float4 v1 = tp[q + 16];
        float4 v2 = tp[q + 32];
        float4 v3 = tp[q + 48];
        float d = v0.x * zm0.x + v0.y * zm0.y + v0.z * zm0.z + v0.w * zm0.w
                + v1.x * zm1.x + v1.y * zm1.y + v1.z * zm1.z + v1.w * zm1.w
                + v2.x * zm2.x + v2.y * zm2.y + v2.z * zm2.z + v2.w * zm2.w
                + v3.x * zm3.x + v3.y * zm3.y + v3.z * zm3.z + v3.w * zm3.w;
        // reduce 16-lane group (per-token dot), then across the 4 groups (window sum)
        d += __shfl_xor(d, 1, 64);
        d += __shfl_xor(d, 2, 64);
        d += __shfl_xor(d, 4, 64);
        d += __shfl_xor(d, 8, 64);
        d += __shfl_xor(d, 16, 64);
        d += __shfl_xor(d, 32, 64);
        if (lane == 0) wout[ww] = d * 0.25f;
    }
}

// ---------------- Kernel 3: per-batch top-3 over 1024 window means ----------------
// 64 blocks (one per batch) x 256 threads
__global__ void k_topk(const float* __restrict__ wmean_g, int* __restrict__ idxout) {
    __shared__ float wmean[1024];
    __shared__ float rv[256];
    __shared__ int   ri[256];
    int b   = blockIdx.x;
    int tid = threadIdx.x;
    for (int widx = tid; widx < 1024; widx += 256) wmean[widx] = wmean_g[b * 1024 + widx];
    __syncthreads();
    for (int k = 0; k < 3; ++k) {
        float bv = -INFINITY;
        int   bi = 1 << 30;
        for (int widx = tid; widx < 1024; widx += 256) {
            float v = wmean[widx];
            if (v > bv || (v == bv && widx < bi)) { bv = v; bi = widx; }
        }
        rv[tid] = bv; ri[tid] = bi;
        __syncthreads();
        for (int s = 128; s > 0; s >>= 1) {
            if (tid < s) {
                float v2 = rv[tid + s]; int i2 = ri[tid + s];
                if (v2 > rv[tid] || (v2 == rv[tid] && i2 < ri[tid])) { rv[tid] = v2; ri[tid] = i2; }
            }
            __syncthreads();
        }
        if (tid == 0) {
            idxout[b * 3 + k] = ri[0];
            wmean[ri[0]] = -INFINITY;
        }
        __syncthreads();
    }
}

// ---------------- Kernel 4: gather + bilinear 2x2->4x4 + gabor modulate ----------------
// grid = B*TOPK = 192 blocks x 256 threads
__global__ void k_out(const float* __restrict__ x, const int* __restrict__ idxbuf,
                      const float* __restrict__ theta, const float* __restrict__ sigma,
                      const float* __restrict__ lam,   const float* __restrict__ psi,
                      const float* __restrict__ gamma, const float* __restrict__ wgt,
                      float* __restrict__ out) {
    __shared__ float Xs[4 * 256];
    __shared__ float gm[16];
    int b = blockIdx.x / 3;
    int k = blockIdx.x % 3;
    int tid  = threadIdx.x;
    int tok  = tid >> 6;   // 0..3 = h2*2+w2
    int lane = tid & 63;

    int widx = idxbuf[b * 3 + k];
    int h0 = (widx >> 5) << 1;
    int w0 = (widx & 31) << 1;
    int token_id = (h0 + (tok >> 1)) * 64 + w0 + (tok & 1);
    float4 v = ((const float4*)(x + ((size_t)b * 4096 + token_id) * 256))[lane];
    ((float4*)Xs)[tok * 64 + lane] = v;

    if (tid < 16) {
        int p = tid;
        float yy = (float)(p >> 2) - 1.5f;
        float xx = (float)(p & 3) - 1.5f;
        float acc = 0.0f;
        for (int kk = 0; kk < 16; ++kk) {
            float th = theta[kk] * TWO_PI;
            float sn, cs;
            sincosf(th, &sn, &cs);
            float xp = xx * cs + yy * sn;
            float yp = -xx * sn + yy * cs;
            float sig = sigma[kk] + 0.5f;
            float lmb = lam[kk] + 0.5f;
            float gam = gamma[kk];
            float env = expf(-(xp * xp + gam * gam * yp * yp) / (2.0f * sig * sig));
            float car = cosf(TWO_PI * xp / lmb + psi[kk]);
            acc += wgt[kk] * env * car;
        }
        gm[p] = 1.0f + acc;
    }
    __syncthreads();

    const float WT[4] = {1.0f, 0.75f, 0.25f, 0.0f};
    float4 x00 = ((const float4*)Xs)[0 * 64 + lane];
    float4 x01 = ((const float4*)Xs)[1 * 64 + lane];
    float4 x10 = ((const float4*)Xs)[2 * 64 + lane];
    float4 x11 = ((const float4*)Xs)[3 * 64 + lane];
    float4* ob = (float4*)(out + ((size_t)b * 48 + k * 16) * 256);
#pragma unroll
    for (int it = 0; it < 4; ++it) {
        int p  = it * 4 + (tid >> 6);
        int gy = p >> 2, gx = p & 3;
        float wy0 = WT[gy], wy1 = 1.0f - wy0;
        float wx0 = WT[gx], wx1 = 1.0f - wx0;
        float g = gm[p];
        float4 r;
        r.x = g * (wy0 * (wx0 * x00.x + wx1 * x01.x) + wy1 * (wx0 * x10.x + wx1 * x11.x));
        r.y = g * (wy0 * (wx0 * x00.y + wx1 * x01.y) + wy1 * (wx0 * x10.y + wx1 * x11.y));
        r.z = g * (wy0 * (wx0 * x00.z + wx1 * x01.z) + wy1 * (wx0 * x10.z + wx1 * x11.z));
        r.w = g * (wy0 * (wx0 * x00.w + wx1 * x01.w) + wy1 * (wx0 * x10.w + wx1 * x11.w));
        ob[(size_t)p * 64 + lane] = r;
    }
}

extern "C" void kernel_launch(void* const* d_in, const int* in_sizes, int n_in,
                              void* d_out, int out_size, void* d_ws, size_t ws_size,
                              hipStream_t stream) {
    const float* z     = (const float*)d_in[0];
    const float* x     = (const float*)d_in[1];
    const float* theta = (const float*)d_in[2];
    const float* sigma = (const float*)d_in[3];
    const float* lam   = (const float*)d_in[4];
    const float* psi   = (const float*)d_in[5];
    const float* gamma = (const float*)d_in[6];
    const float* wgt   = (const float*)d_in[7];
    float* out = (float*)d_out;

    float* ws    = (float*)d_ws;
    float* zmax  = ws;                     // 64*256
    float* wmean = ws + 16384;             // 64*1024
    int*   idxb  = (int*)(ws + 16384 + 65536);  // 64*3

    k_zmax<<<64, 256, 0, stream>>>(z, zmax);
    k_wmean<<<2048, 256, 0, stream>>>(x, zmax, wmean);
    k_topk<<<64, 256, 0, stream>>>(wmean, idxb);
    k_out<<<192, 256, 0, stream>>>(x, idxb, theta, sigma, lam, psi, gamma, wgt, out);
}

// Round 4
// 361.321 us; speedup vs baseline: 1.0695x; 1.0628x over previous
//
#include <hip/hip_runtime.h>
#include <math.h>

#define TWO_PI 6.28318530717958647692f

typedef float vfloat4 __attribute__((ext_vector_type(4)));

// B=64, Nt=64, Ns=4096, C=256, hs=64, WIN=2 -> 32x32=1024 windows/batch, TOPK=3, GH=GW=4

// ---------------- Kernel 1: z_max[b,c] = max_n z[b,n,c] ----------------
__global__ void k_zmax(const float* __restrict__ z, float* __restrict__ zmax) {
    int b = blockIdx.x;          // 64 blocks
    int c = threadIdx.x;         // 256 threads
    const float* zp = z + (size_t)b * 64 * 256 + c;
    float m = -INFINITY;
#pragma unroll
    for (int n = 0; n < 64; ++n) m = fmaxf(m, zp[n * 256]);
    zmax[b * 256 + c] = m;
}

// ---------------- Kernel 2: window means directly ----------------
// wmean[b, wh*32+ww] = 0.25 * sum_{2x2 tokens} dot(x[b,tok,:], zmax[b,:])
// grid = 64 batches * 32 window-rows = 2048 blocks x 256 threads (4 waves).
// Each wave-pass computes ONE window: 16-lane group per token (4 groups),
// each lane covers 16 channels (4 x float4), 6 shfl_xor per window.
// x loads are non-temporal: 256 MB single-use stream, keep it out of L2/L3.
__global__ void k_wmean(const float* __restrict__ x, const float* __restrict__ zmax,
                        float* __restrict__ wmean) {
    int blk  = blockIdx.x;
    int b    = blk >> 5;         // batch
    int wh   = blk & 31;         // window row (0..31)
    int wave = threadIdx.x >> 6; // 0..3
    int lane = threadIdx.x & 63;
    int g    = lane >> 4;        // token within 2x2 window: (g>>1, g&1)
    int q    = lane & 15;        // lane within 16-lane group

    const vfloat4* zm4 = (const vfloat4*)(zmax + b * 256);
    vfloat4 zm0 = zm4[q];
    vfloat4 zm1 = zm4[q + 16];
    vfloat4 zm2 = zm4[q + 32];
    vfloat4 zm3 = zm4[q + 48];

    const vfloat4* xb = (const vfloat4*)(x + (size_t)b * 4096 * 256);
    int trow = (2 * wh + (g >> 1)) * 64;   // token row base
    float* wout = wmean + b * 1024 + wh * 32;

#pragma unroll
    for (int p = 0; p < 8; ++p) {
        int ww  = p * 4 + wave;
        int tok = trow + 2 * ww + (g & 1);
        const vfloat4* tp = xb + (size_t)tok * 64;
        vfloat4 v0 = __builtin_nontemporal_load(tp + q);
        vfloat4 v1 = __builtin_nontemporal_load(tp + q + 16);
        vfloat4 v2 = __builtin_nontemporal_load(tp + q + 32);
        vfloat4 v3 = __builtin_nontemporal_load(tp + q + 48);
        float d = v0.x * zm0.x + v0.y * zm0.y + v0.z * zm0.z + v0.w * zm0.w
                + v1.x * zm1.x + v1.y * zm1.y + v1.z * zm1.z + v1.w * zm1.w
                + v2.x * zm2.x + v2.y * zm2.y + v2.z * zm2.z + v2.w * zm2.w
                + v3.x * zm3.x + v3.y * zm3.y + v3.z * zm3.z + v3.w * zm3.w;
        d += __shfl_xor(d, 1, 64);
        d += __shfl_xor(d, 2, 64);
        d += __shfl_xor(d, 4, 64);
        d += __shfl_xor(d, 8, 64);
        d += __shfl_xor(d, 16, 64);
        d += __shfl_xor(d, 32, 64);
        if (lane == 0) wout[ww] = d * 0.25f;
    }
}

// ---------------- Kernel 3 (fused): top-3 + gather + bilinear + gabor ----------------
// grid = B*TOPK = 192 blocks x 256 threads. Each block redundantly computes the
// per-batch top-3 from wmean (4 KB) and uses its k-th entry.
__global__ void k_out(const float* __restrict__ x, const float* __restrict__ wmean_g,
                      const float* __restrict__ theta, const float* __restrict__ sigma,
                      const float* __restrict__ lam,   const float* __restrict__ psi,
                      const float* __restrict__ gamma, const float* __restrict__ wgt,
                      float* __restrict__ out) {
    __shared__ float wmean[1024];
    __shared__ float rv[256];
    __shared__ int   ri[256];
    __shared__ float Xs[4 * 256];
    __shared__ float gm[16];
    __shared__ int   widx_s;

    int b = blockIdx.x / 3;
    int k = blockIdx.x % 3;
    int tid  = threadIdx.x;
    int tok  = tid >> 6;   // 0..3 = h2*2+w2
    int lane = tid & 63;

    // gabor map (no dependency on topk)
    if (tid < 16) {
        int p = tid;
        float yy = (float)(p >> 2) - 1.5f;
        float xx = (float)(p & 3) - 1.5f;
        float acc = 0.0f;
        for (int kk = 0; kk < 16; ++kk) {
            float th = theta[kk] * TWO_PI;
            float sn, cs;
            sincosf(th, &sn, &cs);
            float xp = xx * cs + yy * sn;
            float yp = -xx * sn + yy * cs;
            float sig = sigma[kk] + 0.5f;
            float lmb = lam[kk] + 0.5f;
            float gam = gamma[kk];
            float env = expf(-(xp * xp + gam * gam * yp * yp) / (2.0f * sig * sig));
            float car = cosf(TWO_PI * xp / lmb + psi[kk]);
            acc += wgt[kk] * env * car;
        }
        gm[p] = 1.0f + acc;
    }

    // load window means
    for (int w = tid; w < 1024; w += 256) wmean[w] = wmean_g[b * 1024 + w];
    __syncthreads();

    // top-3 extraction (stable: strict >, smaller index wins ties — matches lax.top_k)
    for (int kk = 0; kk <= k; ++kk) {
        float bv = -INFINITY;
        int   bi = 1 << 30;
        for (int w = tid; w < 1024; w += 256) {
            float v = wmean[w];
            if (v > bv || (v == bv && w < bi)) { bv = v; bi = w; }
        }
        rv[tid] = bv; ri[tid] = bi;
        __syncthreads();
        for (int s = 128; s > 0; s >>= 1) {
            if (tid < s) {
                float v2 = rv[tid + s]; int i2 = ri[tid + s];
                if (v2 > rv[tid] || (v2 == rv[tid] && i2 < ri[tid])) { rv[tid] = v2; ri[tid] = i2; }
            }
            __syncthreads();
        }
        if (tid == 0) {
            widx_s = ri[0];
            wmean[ri[0]] = -INFINITY;
        }
        __syncthreads();
    }

    int widx = widx_s;
    int h0 = (widx >> 5) << 1;
    int w0 = (widx & 31) << 1;
    int token_id = (h0 + (tok >> 1)) * 64 + w0 + (tok & 1);
    float4 v = ((const float4*)(x + ((size_t)b * 4096 + token_id) * 256))[lane];
    ((float4*)Xs)[tok * 64 + lane] = v;
    __syncthreads();

    const float WT[4] = {1.0f, 0.75f, 0.25f, 0.0f};
    float4 x00 = ((const float4*)Xs)[0 * 64 + lane];
    float4 x01 = ((const float4*)Xs)[1 * 64 + lane];
    float4 x10 = ((const float4*)Xs)[2 * 64 + lane];
    float4 x11 = ((const float4*)Xs)[3 * 64 + lane];
    float4* ob = (float4*)(out + ((size_t)b * 48 + k * 16) * 256);
#pragma unroll
    for (int it = 0; it < 4; ++it) {
        int p  = it * 4 + (tid >> 6);
        int gy = p >> 2, gx = p & 3;
        float wy0 = WT[gy], wy1 = 1.0f - wy0;
        float wx0 = WT[gx], wx1 = 1.0f - wx0;
        float g = gm[p];
        float4 r;
        r.x = g * (wy0 * (wx0 * x00.x + wx1 * x01.x) + wy1 * (wx0 * x10.x + wx1 * x11.x));
        r.y = g * (wy0 * (wx0 * x00.y + wx1 * x01.y) + wy1 * (wx0 * x10.y + wx1 * x11.y));
        r.z = g * (wy0 * (wx0 * x00.z + wx1 * x01.z) + wy1 * (wx0 * x10.z + wx1 * x11.z));
        r.w = g * (wy0 * (wx0 * x00.w + wx1 * x01.w) + wy1 * (wx0 * x10.w + wx1 * x11.w));
        ob[(size_t)p * 64 + lane] = r;
    }
}

extern "C" void kernel_launch(void* const* d_in, const int* in_sizes, int n_in,
                              void* d_out, int out_size, void* d_ws, size_t ws_size,
                              hipStream_t stream) {
    const float* z     = (const float*)d_in[0];
    const float* x     = (const float*)d_in[1];
    const float* theta = (const float*)d_in[2];
    const float* sigma = (const float*)d_in[3];
    const float* lam   = (const float*)d_in[4];
    const float* psi   = (const float*)d_in[5];
    const float* gamma = (const float*)d_in[6];
    const float* wgt   = (const float*)d_in[7];
    float* out = (float*)d_out;

    float* ws    = (float*)d_ws;
    float* zmax  = ws;           // 64*256
    float* wmean = ws + 16384;   // 64*1024

    k_zmax<<<64, 256, 0, stream>>>(z, zmax);
    k_wmean<<<2048, 256, 0, stream>>>(x, zmax, wmean);
    k_out<<<192, 256, 0, stream>>>(x, wmean, theta, sigma, lam, psi, gamma, wgt, out);
}